// Round 1
// baseline (143.431 us; speedup 1.0000x reference)
//
#include <hip/hip_runtime.h>
#include <stdint.h>

typedef _Float16 half8 __attribute__((ext_vector_type(8)));
typedef _Float16 half4 __attribute__((ext_vector_type(4)));
typedef __fp16   fp16x2 __attribute__((ext_vector_type(2)));
typedef float    floatx4 __attribute__((ext_vector_type(4)));
typedef unsigned uintx2 __attribute__((ext_vector_type(2)));
typedef unsigned uintx4 __attribute__((ext_vector_type(4)));

#define T_LEN 2048
#define CH 64
#define BH 32            // bs * n_heads
#define QTILE 128        // t per block (32 per wave)
#define LDP 72           // prep LDS pad (halves)
#define FRAG_BH 131072   // halves per bh per tensor (64*2048)

// ---------------- pass 1: fp32 -> fp16, reorder into MFMA fragment order ----------
// Q pre-scaled by 0.125 * rescale * log2(e) so attention does raw exp2.
// QF/KF[bh][g][ks][lane][8]: g = t(or s)>>4, element = X[c = ks*32+quad*8+j][t = g*16+l15]
// VF[bh][stile64][ct*2+ks][lane][8]: element = V[c = ct*16+l15][s = stile64*64+ks*32+quad*8+j]
__global__ __launch_bounds__(256, 2)
void prep_kernel(const float* __restrict__ qkv, const float* __restrict__ rescale,
                 _Float16* __restrict__ ws)
{
    __shared__ _Float16 Qs[64][LDP];   // [t][c]
    __shared__ _Float16 Ks[64][LDP];   // [s][c]
    __shared__ _Float16 Vs[64][LDP];   // [c][s]

    const int tid  = threadIdx.x;
    const int bh   = blockIdx.y;
    const int tile = blockIdx.x;       // 64-element tile along t/s
    const int x0   = tile * 64;

    const float qscale = 0.125f * 1.4426950408889634f * rescale[0];

    const float* qp = qkv + (size_t)(bh >> 3) * (1536 * T_LEN)
                          + (size_t)(bh & 7) * (192 * T_LEN);
    const float* kp = qp + 64 * T_LEN;
    const float* vp = qp + 128 * T_LEN;

    // Q,K: 4x4 register-block transpose [c][t] -> [t][c]
    {
        const int a4 = (tid & 15) * 4;
        const int c4 = (tid >> 4) * 4;
        float4 rq[4], rk[4];
#pragma unroll
        for (int i = 0; i < 4; ++i) {
            rq[i] = *(const float4*)(qp + (size_t)(c4 + i) * T_LEN + x0 + a4);
            rk[i] = *(const float4*)(kp + (size_t)(c4 + i) * T_LEN + x0 + a4);
        }
#pragma unroll
        for (int j = 0; j < 4; ++j) {
            half4 hq, hk;
#pragma unroll
            for (int i = 0; i < 4; ++i) {
                hq[i] = (_Float16)((&rq[i].x)[j] * qscale);
                hk[i] = (_Float16)((&rk[i].x)[j]);
            }
            *(half4*)&Qs[a4 + j][c4] = hq;
            *(half4*)&Ks[a4 + j][c4] = hk;
        }
        // V natural [c][s]
        const int s4 = (tid & 15) * 4;
        const int cv = tid >> 4;
#pragma unroll
        for (int i = 0; i < 4; ++i) {
            const int c = cv + 16 * i;
            float4 r = *(const float4*)(vp + (size_t)c * T_LEN + x0 + s4);
            half4 h; h[0]=(_Float16)r.x; h[1]=(_Float16)r.y; h[2]=(_Float16)r.z; h[3]=(_Float16)r.w;
            *(half4*)&Vs[c][s4] = h;
        }
    }
    __syncthreads();

    const int lane = tid & 63, wave = tid >> 6;
    const int l15 = lane & 15, quad = lane >> 4;
    _Float16* qf = ws;
    _Float16* kf = ws + (size_t)BH * FRAG_BH;
    _Float16* vf = ws + (size_t)2 * BH * FRAG_BH;

#pragma unroll
    for (int ks = 0; ks < 2; ++ks) {
        half8 hq = *(const half8*)&Qs[wave * 16 + l15][ks * 32 + quad * 8];
        half8 hk = *(const half8*)&Ks[wave * 16 + l15][ks * 32 + quad * 8];
        half8 hv = *(const half8*)&Vs[wave * 16 + l15][ks * 32 + quad * 8];
        const size_t gqk = (((size_t)bh * 128 + tile * 4 + wave) * 2 + ks) * 512 + lane * 8;
        *(half8*)(qf + gqk) = hq;
        *(half8*)(kf + gqk) = hk;
        *(half8*)(vf + (((size_t)bh * 32 + tile) * 8 + wave * 2 + ks) * 512 + lane * 8) = hv;
    }
}

// ---------------- pass 2: attention, barrier-free, register-pipelined --------------
// NO __syncthreads, NO LDS. Waves free-run and anti-phase (one wave's exp/VALU
// overlaps another's MFMA). K and V fragments are loaded per-wave directly from ws
// (the block's 4 waves read identical addresses -> L1/L2 served), each issued a FULL
// iteration before use. The P layout transform (QK output frag -> PV A-operand frag)
// is done IN-REGISTER: the required redistribution is only among the 4 lanes sharing
// l15 (quads), realized as permlane32_swap + permlane16_swap per word pair.
//   u[ks][j2](lane q) = w[2ks + (q>>1)][j2&1] from quad ((q&1)*2 + (j2>>1))
//   permlane32_swap(a,b) -> (a0,a1,b0,b1),(a2,a3,b2,b3)   [rows of 16 lanes]
//   permlane16_swap(x,y) -> (x0,y0,x2,y2),(x1,y1,x3,y3)
//   => (a0,a2,b0,b2) = u[ks][h], (a1,a3,b1,b3) = u[ks][2+h]
__global__ __launch_bounds__(256, 2)
void attn_kernel(const _Float16* __restrict__ ws, float* __restrict__ out)
{
    const int tid  = threadIdx.x;
    const int wave = tid >> 6;
    const int lane = tid & 63;
    const int l15  = lane & 15;
    const int quad = lane >> 4;

    // XCD-aware decode: consecutive blockIdx round-robin over the 8 XCDs, so put
    // all 16 t-tiles of one bh on ONE XCD. Each XCD then holds 4 bh x 512 KB = 2 MB
    // of K/V in its 4 MB L2 -> K/V fetched from HBM once instead of ~3x.
    const int bid  = blockIdx.x;        // 0..511
    const int xcd  = bid & 7;
    const int slot = bid >> 3;          // 0..63
    const int bh   = (slot >> 4) * 8 + xcd;
    const int tile = slot & 15;
    const int t0   = tile * QTILE;

    const _Float16* qf = ws;
    const _Float16* kf = ws + (size_t)BH * FRAG_BH;
    const _Float16* vf = ws + (size_t)2 * BH * FRAG_BH;
    float* op = out + (size_t)bh * (CH * T_LEN);

    const _Float16* kfp = kf + (size_t)bh * FRAG_BH + lane * 8;
    const _Float16* vfp = vf + (size_t)bh * FRAG_BH + lane * 8;

    // Q fragments: persistent (Q pre-scaled in prep); 32 t/wave = 2 t-groups
    half8 bq[2][2];
#pragma unroll
    for (int tb = 0; tb < 2; ++tb)
#pragma unroll
        for (int ks = 0; ks < 2; ++ks)
            bq[tb][ks] = *(const half8*)(qf +
                (((size_t)bh * 128 + tile * 8 + wave * 2 + tb) * 2 + ks) * 512 + lane * 8);

    const floatx4 fzero = {0.f, 0.f, 0.f, 0.f};
    floatx4 oacc[2][4];                 // [tb][ctile]
#pragma unroll
    for (int tb = 0; tb < 2; ++tb)
#pragma unroll
        for (int ct = 0; ct < 4; ++ct) oacc[tb][ct] = fzero;
    floatx4 lacc[2] = {fzero, fzero};   // row sums via ones-MFMA

    half8 bones;
#pragma unroll
    for (int i = 0; i < 8; ++i) bones[i] = (_Float16)1.0f;

    half8 ak[4][2];    // K(st): loaded one iteration ahead of its QK
    half8 bv[4][2];    // V(st-1) at loop top
    half8 ap[2][2];    // P(st-1) at loop top

    // QK + exp + in-register transpose for tile st using current ak
    auto do_qk_exp = [&]() {
        floatx4 sacc[4][2];
#pragma unroll
        for (int mt = 0; mt < 4; ++mt)
#pragma unroll
            for (int tb = 0; tb < 2; ++tb) sacc[mt][tb] = fzero;
#pragma unroll
        for (int mt = 0; mt < 4; ++mt)
#pragma unroll
            for (int tb = 0; tb < 2; ++tb)
#pragma unroll
                for (int ks = 0; ks < 2; ++ks)
                    sacc[mt][tb] = __builtin_amdgcn_mfma_f32_16x16x32_f16(
                        ak[mt][ks], bq[tb][ks], sacc[mt][tb], 0, 0, 0);

        // p = exp2(logit), packed f32->f16; lane owns t=l15, s = mt*16+quad*4+r
        // w[mt][h] = halves of P at s = mt*16 + quad*4 + 2h + {0,1}
#pragma unroll
        for (int tb = 0; tb < 2; ++tb) {
            unsigned w[4][2];
#pragma unroll
            for (int mt = 0; mt < 4; ++mt) {
                fp16x2 p01 = __builtin_amdgcn_cvt_pkrtz(
                    __builtin_amdgcn_exp2f(sacc[mt][tb][0]),
                    __builtin_amdgcn_exp2f(sacc[mt][tb][1]));
                fp16x2 p23 = __builtin_amdgcn_cvt_pkrtz(
                    __builtin_amdgcn_exp2f(sacc[mt][tb][2]),
                    __builtin_amdgcn_exp2f(sacc[mt][tb][3]));
                w[mt][0] = __builtin_bit_cast(unsigned, p01);
                w[mt][1] = __builtin_bit_cast(unsigned, p23);
            }
#pragma unroll
            for (int ks = 0; ks < 2; ++ks) {
                uintx4 uu;
                {   // h = 0 -> u[ks][0], u[ks][2]
                    uintx2 s1 = __builtin_amdgcn_permlane32_swap(
                        w[2 * ks][0], w[2 * ks + 1][0], false, false);
                    uintx2 s2 = __builtin_amdgcn_permlane16_swap(
                        s1[0], s1[1], false, false);
                    uu[0] = s2[0]; uu[2] = s2[1];
                }
                {   // h = 1 -> u[ks][1], u[ks][3]
                    uintx2 s1 = __builtin_amdgcn_permlane32_swap(
                        w[2 * ks][1], w[2 * ks + 1][1], false, false);
                    uintx2 s2 = __builtin_amdgcn_permlane16_swap(
                        s1[0], s1[1], false, false);
                    uu[1] = s2[0]; uu[3] = s2[1];
                }
                ap[tb][ks] = __builtin_bit_cast(half8, uu);
            }
        }
    };

    // ---- prologue: tile 0
#pragma unroll
    for (int mt = 0; mt < 4; ++mt)
#pragma unroll
        for (int ks = 0; ks < 2; ++ks)
            ak[mt][ks] = *(const half8*)(kfp + (size_t)(mt * 2 + ks) * 512);
#pragma unroll
    for (int ct = 0; ct < 4; ++ct)
#pragma unroll
        for (int ks = 0; ks < 2; ++ks)
            bv[ct][ks] = *(const half8*)(vfp + (size_t)(ct * 2 + ks) * 512);
    do_qk_exp();
    // K(1) issued now (full iteration to land)
#pragma unroll
    for (int mt = 0; mt < 4; ++mt)
#pragma unroll
        for (int ks = 0; ks < 2; ++ks)
            ak[mt][ks] = *(const half8*)(kfp + 4096 + (size_t)(mt * 2 + ks) * 512);

    // ---- main loop
#pragma unroll 2
    for (int st = 1; st < 32; ++st) {
        // PV(st-1): operands resolved; independent MFMA work at iteration top
#pragma unroll
        for (int tb = 0; tb < 2; ++tb)
#pragma unroll
            for (int ks = 0; ks < 2; ++ks)
                lacc[tb] = __builtin_amdgcn_mfma_f32_16x16x32_f16(ap[tb][ks], bones, lacc[tb], 0, 0, 0);
#pragma unroll
        for (int tb = 0; tb < 2; ++tb)
#pragma unroll
            for (int ct = 0; ct < 4; ++ct)
#pragma unroll
                for (int ks = 0; ks < 2; ++ks)
                    oacc[tb][ct] = __builtin_amdgcn_mfma_f32_16x16x32_f16(
                        ap[tb][ks], bv[ct][ks], oacc[tb][ct], 0, 0, 0);

        // V(st): issue now, consumed at next iteration's PV
        const _Float16* vcur = vfp + (size_t)st * 4096;
#pragma unroll
        for (int ct = 0; ct < 4; ++ct)
#pragma unroll
            for (int ks = 0; ks < 2; ++ks)
                bv[ct][ks] = *(const half8*)(vcur + (size_t)(ct * 2 + ks) * 512);

        // QK(st) with ak (issued one iteration ago), then exp -> permlane -> ap
        do_qk_exp();

        // K(st+1): issue now, consumed at next iteration's QK
        if (st < 31) {
            const _Float16* kcur = kfp + (size_t)(st + 1) * 4096;
#pragma unroll
            for (int mt = 0; mt < 4; ++mt)
#pragma unroll
                for (int ks = 0; ks < 2; ++ks)
                    ak[mt][ks] = *(const half8*)(kcur + (size_t)(mt * 2 + ks) * 512);
        }
    }

    // ---- epilogue: PV(31)
#pragma unroll
    for (int tb = 0; tb < 2; ++tb)
#pragma unroll
        for (int ks = 0; ks < 2; ++ks)
            lacc[tb] = __builtin_amdgcn_mfma_f32_16x16x32_f16(ap[tb][ks], bones, lacc[tb], 0, 0, 0);
#pragma unroll
    for (int tb = 0; tb < 2; ++tb)
#pragma unroll
        for (int ct = 0; ct < 4; ++ct)
#pragma unroll
            for (int ks = 0; ks < 2; ++ks)
                oacc[tb][ct] = __builtin_amdgcn_mfma_f32_16x16x32_f16(
                    ap[tb][ks], bv[ct][ks], oacc[tb][ct], 0, 0, 0);

    // normalize + store: col = c = ct*16 + l15, rows t = t0 + wave*32 + tb*16 + quad*4 + r
#pragma unroll
    for (int tb = 0; tb < 2; ++tb) {
        float linv[4];
#pragma unroll
        for (int r = 0; r < 4; ++r) linv[r] = 1.0f / lacc[tb][r];
#pragma unroll
        for (int ct = 0; ct < 4; ++ct) {
            const int c = ct * 16 + l15;
            const int t = t0 + wave * 32 + tb * 16 + quad * 4;
            float4 o;
#pragma unroll
            for (int r = 0; r < 4; ++r)
                (&o.x)[r] = oacc[tb][ct][r] * linv[r];
            *(float4*)(op + (size_t)c * T_LEN + t) = o;
        }
    }
}

extern "C" void kernel_launch(void* const* d_in, const int* in_sizes, int n_in,
                              void* d_out, int out_size, void* d_ws, size_t ws_size,
                              hipStream_t stream) {
    const float* qkv     = (const float*)d_in[0];
    const float* rescale = (const float*)d_in[1];
    float* out = (float*)d_out;
    _Float16* ws = (_Float16*)d_ws;   // needs 3*32*131072*2 B = 25.2 MB

    prep_kernel<<<dim3(32, BH), dim3(256), 0, stream>>>(qkv, rescale, ws);
    attn_kernel<<<dim3(T_LEN / QTILE * BH), dim3(256), 0, stream>>>(ws, out);
}